// Round 1
// baseline (1691.972 us; speedup 1.0000x reference)
//
#include <hip/hip_runtime.h>

#define S 132            // padded LDS row stride (floats): 128 + 4
#define SCALE 10.0f      // 1 / TEMPERATURE

// ---------- K1: l2-normalize rows of p1,p2 into pn[4096][128]; zero `best` ----
__global__ void k_normalize(const float* __restrict__ p1,
                            const float* __restrict__ p2,
                            float* __restrict__ pn,
                            unsigned long long* __restrict__ best) {
    int row = blockIdx.x;               // 0..4095
    int t = threadIdx.x;                // 0..63
    const float* src = (row < 2048) ? (p1 + (size_t)row * 128)
                                    : (p2 + (size_t)(row - 2048) * 128);
    float2 v = ((const float2*)src)[t];
    float ss = v.x * v.x + v.y * v.y;
    #pragma unroll
    for (int o = 32; o; o >>= 1) ss += __shfl_xor(ss, o);
    float inv = 1.0f / sqrtf(ss);
    float2 o2; o2.x = v.x * inv; o2.y = v.y * inv;
    ((float2*)(pn + (size_t)row * 128))[t] = o2;
    if (t == 0) best[row] = 0ULL;       // packed (ordered-float, ~idx); 0 = -inf
}

// ---------- helper: map float to order-preserving uint ----------
__device__ __forceinline__ unsigned int ordered_bits(float f) {
    unsigned int b = __float_as_uint(f);
    return b ^ ((b & 0x80000000u) ? 0xFFFFFFFFu : 0x80000000u);
}

// ---------- K2: per-row argmax over queue dots (fp32 tiled GEMM-reduce) -------
// grid (64 rowblocks, 16 qchunks), 256 threads. Tile: 64 rows x 64 q, K=128.
__global__ __launch_bounds__(256) void k_argmax(const float* __restrict__ pn,
                                                const float* __restrict__ queue,
                                                unsigned long long* __restrict__ best) {
    __shared__ __align__(16) float pl[64 * S];
    __shared__ __align__(16) float ql[64 * S];
    int tid = threadIdx.x;
    int rb = blockIdx.x;                // row block: rows rb*64..+63
    int qc = blockIdx.y;                // q chunk: 4096 q's

    // stage p tile (once)
    const float4* psrc = (const float4*)(pn + (size_t)rb * 64 * 128);
    #pragma unroll
    for (int i = tid; i < 2048; i += 256) {
        int r = i >> 5, c = i & 31;
        *(float4*)&pl[r * S + c * 4] = psrc[i];
    }

    int ty = tid >> 4, tx = tid & 15;   // rows ty+16i, cols tx+16j (bank-friendly)
    unsigned long long tbest[4] = {0ULL, 0ULL, 0ULL, 0ULL};

    for (int qt = 0; qt < 64; ++qt) {
        int qbase = qc * 4096 + qt * 64;
        __syncthreads();                // previous tile fully consumed (and pl staged)
        const float4* qsrc = (const float4*)(queue + (size_t)qbase * 128);
        #pragma unroll
        for (int i = tid; i < 2048; i += 256) {
            int r = i >> 5, c = i & 31;
            *(float4*)&ql[r * S + c * 4] = qsrc[i];
        }
        __syncthreads();

        float acc[4][4] = {};
        #pragma unroll 2
        for (int k = 0; k < 128; k += 4) {
            float4 a[4], b[4];
            #pragma unroll
            for (int i = 0; i < 4; ++i) a[i] = *(const float4*)&pl[(ty + 16 * i) * S + k];
            #pragma unroll
            for (int j = 0; j < 4; ++j) b[j] = *(const float4*)&ql[(tx + 16 * j) * S + k];
            #pragma unroll
            for (int i = 0; i < 4; ++i)
                #pragma unroll
                for (int j = 0; j < 4; ++j)
                    acc[i][j] += a[i].x * b[j].x + a[i].y * b[j].y +
                                 a[i].z * b[j].z + a[i].w * b[j].w;
        }
        #pragma unroll
        for (int i = 0; i < 4; ++i) {
            #pragma unroll
            for (int j = 0; j < 4; ++j) {
                unsigned int q = (unsigned int)(qbase + tx + 16 * j);
                unsigned long long pk =
                    ((unsigned long long)ordered_bits(acc[i][j]) << 32) |
                    (unsigned long long)(unsigned int)(~q);
                if (pk > tbest[i]) tbest[i] = pk;
            }
        }
    }

    // merge across tx (16 threads per row), then atomic to global
    __syncthreads();
    unsigned long long* sc = (unsigned long long*)pl;   // 64 rows x 16 = 8 KB
    #pragma unroll
    for (int i = 0; i < 4; ++i) sc[(ty + 16 * i) * 16 + tx] = tbest[i];
    __syncthreads();
    if (tid < 64) {
        unsigned long long m = sc[tid * 16];
        #pragma unroll
        for (int x = 1; x < 16; ++x) {
            unsigned long long v = sc[tid * 16 + x];
            if (v > m) m = v;
        }
        atomicMax(&best[rb * 64 + tid], m);
    }
}

// ---------- K3: gather nn rows from queue ----------
__global__ void k_gather(const float* __restrict__ queue,
                         const unsigned long long* __restrict__ best,
                         float* __restrict__ nn) {
    int row = blockIdx.x;               // 0..4095
    int t = threadIdx.x;                // 0..63
    unsigned int idx = ~(unsigned int)(best[row] & 0xFFFFFFFFull);
    ((float2*)(nn + (size_t)row * 128))[t] =
        ((const float2*)(queue + (size_t)idx * 128))[t];
}

// ---------- K4: C = A @ B^T, A,B [2048x128], C [2048x2048] ----------
__global__ __launch_bounds__(256) void k_gemm_bt(const float* __restrict__ A,
                                                 const float* __restrict__ B,
                                                 float* __restrict__ C) {
    __shared__ __align__(16) float al[64 * S];
    __shared__ __align__(16) float bl[64 * S];
    int tid = threadIdx.x;
    const float4* asrc = (const float4*)(A + (size_t)blockIdx.x * 64 * 128);
    const float4* bsrc = (const float4*)(B + (size_t)blockIdx.y * 64 * 128);
    #pragma unroll
    for (int i = tid; i < 2048; i += 256) {
        int r = i >> 5, c = i & 31;
        *(float4*)&al[r * S + c * 4] = asrc[i];
        *(float4*)&bl[r * S + c * 4] = bsrc[i];
    }
    __syncthreads();
    int ty = tid >> 4, tx = tid & 15;
    float acc[4][4] = {};
    #pragma unroll 2
    for (int k = 0; k < 128; k += 4) {
        float4 a[4], b[4];
        #pragma unroll
        for (int i = 0; i < 4; ++i) a[i] = *(const float4*)&al[(ty + 16 * i) * S + k];
        #pragma unroll
        for (int j = 0; j < 4; ++j) b[j] = *(const float4*)&bl[(tx + 16 * j) * S + k];
        #pragma unroll
        for (int i = 0; i < 4; ++i)
            #pragma unroll
            for (int j = 0; j < 4; ++j)
                acc[i][j] += a[i].x * b[j].x + a[i].y * b[j].y +
                             a[i].z * b[j].z + a[i].w * b[j].w;
    }
    int rowbase = blockIdx.x * 64, colbase = blockIdx.y * 64;
    #pragma unroll
    for (int i = 0; i < 4; ++i)
        #pragma unroll
        for (int j = 0; j < 4; ++j)
            C[(size_t)(rowbase + ty + 16 * i) * 2048 + (colbase + tx + 16 * j)] = acc[i][j];
}

// ---------- K5: row-wise LSE minus diag ----------
__global__ void k_row_lse(const float* __restrict__ M, float* __restrict__ out) {
    int row = blockIdx.x;               // 0..2047
    int tid = threadIdx.x;              // 0..255
    __shared__ float sm[256], ssb[256];
    float m = -1e30f, s = 0.0f;
    for (int j = tid; j < 2048; j += 256) {
        float x = M[(size_t)row * 2048 + j] * SCALE;
        if (x > m) { s = s * expf(m - x) + 1.0f; m = x; }
        else s += expf(x - m);
    }
    sm[tid] = m; ssb[tid] = s; __syncthreads();
    for (int w = 128; w; w >>= 1) {
        if (tid < w) {
            float m2 = sm[tid + w], s2 = ssb[tid + w];
            float mm = fmaxf(sm[tid], m2);
            ssb[tid] = ssb[tid] * expf(sm[tid] - mm) + s2 * expf(m2 - mm);
            sm[tid] = mm;
        }
        __syncthreads();
    }
    if (tid == 0)
        out[row] = sm[0] + logf(ssb[0]) - M[(size_t)row * 2048 + row] * SCALE;
}

// ---------- K6: column-wise LSE minus diag ----------
__global__ void k_col_lse(const float* __restrict__ M, float* __restrict__ out) {
    int c0 = blockIdx.x * 64;           // 32 blocks x 64 cols
    int tid = threadIdx.x;              // 0..255
    int col = c0 + (tid & 63);
    int g = tid >> 6;                   // 4 row groups
    __shared__ float sm[256], ssb[256];
    float m = -1e30f, s = 0.0f;
    for (int r = g; r < 2048; r += 4) {
        float x = M[(size_t)r * 2048 + col] * SCALE;
        if (x > m) { s = s * expf(m - x) + 1.0f; m = x; }
        else s += expf(x - m);
    }
    sm[tid] = m; ssb[tid] = s; __syncthreads();
    if (tid < 64) {
        float mm = sm[tid], ss = ssb[tid];
        #pragma unroll
        for (int gg = 1; gg < 4; ++gg) {
            float m2 = sm[tid + 64 * gg], s2 = ssb[tid + 64 * gg];
            float mx = fmaxf(mm, m2);
            ss = ss * expf(mm - mx) + s2 * expf(m2 - mx);
            mm = mx;
        }
        out[col] = mm + logf(ss) - M[(size_t)col * 2048 + col] * SCALE;
    }
}

extern "C" void kernel_launch(void* const* d_in, const int* in_sizes, int n_in,
                              void* d_out, int out_size, void* d_ws, size_t ws_size,
                              hipStream_t stream) {
    const float* p1    = (const float*)d_in[0];   // [2048,128]
    const float* p2    = (const float*)d_in[1];   // [2048,128]
    const float* queue = (const float*)d_in[2];   // [65536,128]
    float* out = (float*)d_out;                   // [8192]

    float* ws = (float*)d_ws;
    float* pn = ws;                                       // 4096*128
    float* nn = ws + 524288;                              // 4096*128
    unsigned long long* best = (unsigned long long*)(ws + 1048576); // 4096 u64
    float* M = ws + 1048576 + 8192;                       // 2048*2048

    k_normalize<<<4096, 64, 0, stream>>>(p1, p2, pn, best);
    k_argmax<<<dim3(64, 16), 256, 0, stream>>>(pn, queue, best);
    k_gather<<<4096, 64, 0, stream>>>(queue, best, nn);

    // M1 = nn1 @ p2n^T -> rows: loss[0..2047], cols: loss[2048..4095]
    k_gemm_bt<<<dim3(32, 32), 256, 0, stream>>>(nn, pn + 2048 * 128, M);
    k_row_lse<<<2048, 256, 0, stream>>>(M, out);
    k_col_lse<<<32, 256, 0, stream>>>(M, out + 2048);

    // M2 = nn2 @ p1n^T -> rows: loss[4096..6143], cols: loss[6144..8191]
    k_gemm_bt<<<dim3(32, 32), 256, 0, stream>>>(nn + 2048 * 128, pn, M);
    k_row_lse<<<2048, 256, 0, stream>>>(M, out + 4096);
    k_col_lse<<<32, 256, 0, stream>>>(M, out + 6144);
}

// Round 2
// 729.786 us; speedup vs baseline: 2.3184x; 2.3184x over previous
//
#include <hip/hip_runtime.h>

#define S 132                 // padded LDS row stride (floats) for gemm tiles
#define SCALE 10.0f           // 1 / TEMPERATURE
#define EPS_MARGIN 0.008f     // 2 * (bf16 unit-vector dot hard error bound 2^-8)
#define CAND_CAP 16384

typedef __attribute__((ext_vector_type(8))) short short8;
typedef __attribute__((ext_vector_type(4))) float floatx4;

#define MFMA16(a, b, c) __builtin_amdgcn_mfma_f32_16x16x32_bf16((a), (b), (c), 0, 0, 0)

// ---------- helpers ----------
__device__ __forceinline__ unsigned int ordered_bits(float f) {
    unsigned int b = __float_as_uint(f);
    return (b & 0x80000000u) ? ~b : (b | 0x80000000u);
}
__device__ __forceinline__ float from_ordered(unsigned int u) {
    return __uint_as_float((u & 0x80000000u) ? (u ^ 0x80000000u) : ~u);
}
__device__ __forceinline__ short bf_rne(float x) {   // fp32 -> bf16 bits, RNE
    unsigned int u = __float_as_uint(x);
    return (short)((u + 0x7FFFu + ((u >> 16) & 1u)) >> 16);
}
__device__ __forceinline__ float bf2f(short s) {
    return __uint_as_float(((unsigned int)(unsigned short)s) << 16);
}

// ---------- K1: l2-normalize p1,p2 -> pn fp32; init mbest/best/cnt ----------
__global__ void k_prep(const float* __restrict__ p1, const float* __restrict__ p2,
                       float* __restrict__ pn, unsigned int* __restrict__ mbest,
                       unsigned long long* __restrict__ best, unsigned int* __restrict__ cnt) {
    int row = blockIdx.x;               // 0..4095
    int t = threadIdx.x;                // 0..63
    const float* src = (row < 2048) ? (p1 + (size_t)row * 128)
                                    : (p2 + (size_t)(row - 2048) * 128);
    float2 v = ((const float2*)src)[t];
    float ss = v.x * v.x + v.y * v.y;
    #pragma unroll
    for (int o = 32; o; o >>= 1) ss += __shfl_xor(ss, o);
    float inv = 1.0f / sqrtf(ss);
    float2 o2; o2.x = v.x * inv; o2.y = v.y * inv;
    ((float2*)(pn + (size_t)row * 128))[t] = o2;
    if (t == 0) { mbest[row] = 0u; best[row] = 0ULL; if (row == 0) *cnt = 0u; }
}

// ---------- K2: queue fp32 -> qb bf16 ----------
__global__ void k_qcvt(const float* __restrict__ queue, short* __restrict__ qb) {
    size_t i = ((size_t)blockIdx.x * 256 + threadIdx.x) * 8;
    float4 f0 = *(const float4*)(queue + i);
    float4 f1 = *(const float4*)(queue + i + 4);
    short8 o;
    o[0] = bf_rne(f0.x); o[1] = bf_rne(f0.y); o[2] = bf_rne(f0.z); o[3] = bf_rne(f0.w);
    o[4] = bf_rne(f1.x); o[5] = bf_rne(f1.y); o[6] = bf_rne(f1.z); o[7] = bf_rne(f1.w);
    *(short8*)(qb + i) = o;
}

// ---------- K3/K4: bf16 MFMA screen. MODE 0: per-row max; MODE 1: candidates --
// grid (32 rowblocks, 16 qsplits), 256 threads (4 waves). Wave: 128 rows x 1024 q.
// A frags (128 rows x K=128) held in registers; B streamed from global (L3-hot).
template <int MODE>
__global__ __launch_bounds__(256, 2) void k_screen(const float* __restrict__ pn,
                                                   const short* __restrict__ qb,
                                                   unsigned int* __restrict__ mbest,
                                                   unsigned int* __restrict__ cnt,
                                                   unsigned long long* __restrict__ cand) {
    int tid = threadIdx.x;
    int lane = tid & 63, wv = tid >> 6;
    int n16 = lane & 15, quad = lane >> 4;
    int rowbase = blockIdx.x * 128;
    int qstart = blockIdx.y * 4096 + wv * 1024;

    // load + convert A fragments (one-time): A[m=lane&15][k=quad*8+j]
    short8 A[8][4];
    #pragma unroll
    for (int rf = 0; rf < 8; ++rf) {
        const float* ap = pn + (size_t)(rowbase + rf * 16 + n16) * 128 + quad * 8;
        #pragma unroll
        for (int k = 0; k < 4; ++k) {
            float4 f0 = *(const float4*)(ap + 32 * k);
            float4 f1 = *(const float4*)(ap + 32 * k + 4);
            short8 a;
            a[0] = bf_rne(f0.x); a[1] = bf_rne(f0.y); a[2] = bf_rne(f0.z); a[3] = bf_rne(f0.w);
            a[4] = bf_rne(f1.x); a[5] = bf_rne(f1.y); a[6] = bf_rne(f1.z); a[7] = bf_rne(f1.w);
            A[rf][k] = a;
        }
    }

    float rmax[8][4];
    float thr[8][4];
    #pragma unroll
    for (int rf = 0; rf < 8; ++rf)
        #pragma unroll
        for (int r = 0; r < 4; ++r) {
            if (MODE == 0) rmax[rf][r] = -1e30f;
            else thr[rf][r] = from_ordered(mbest[rowbase + rf * 16 + quad * 4 + r]) - EPS_MARGIN;
        }

    const short* lp = qb + (size_t)(qstart + n16) * 128 + quad * 8;
    short8 bc0 = *(const short8*)(lp), bc1 = *(const short8*)(lp + 32),
           bc2 = *(const short8*)(lp + 64), bc3 = *(const short8*)(lp + 96);
    floatx4 zero = {0.0f, 0.0f, 0.0f, 0.0f};

    for (int t = 0; t < 64; ++t) {
        const short* nlp = lp + 2048;           // next 16-q tile (prefetch; tail read stays in ws)
        short8 bn0 = *(const short8*)(nlp), bn1 = *(const short8*)(nlp + 32),
               bn2 = *(const short8*)(nlp + 64), bn3 = *(const short8*)(nlp + 96);
        #pragma unroll
        for (int rf = 0; rf < 8; ++rf) {
            floatx4 acc = MFMA16(A[rf][0], bc0, zero);
            acc = MFMA16(A[rf][1], bc1, acc);
            acc = MFMA16(A[rf][2], bc2, acc);
            acc = MFMA16(A[rf][3], bc3, acc);
            if (MODE == 0) {
                #pragma unroll
                for (int r = 0; r < 4; ++r) rmax[rf][r] = fmaxf(rmax[rf][r], acc[r]);
            } else {
                #pragma unroll
                for (int r = 0; r < 4; ++r) {
                    if (acc[r] > thr[rf][r]) {
                        unsigned int pos = atomicAdd(cnt, 1u);
                        if (pos < CAND_CAP)
                            cand[pos] = ((unsigned long long)(unsigned int)(rowbase + rf * 16 + quad * 4 + r) << 32)
                                      | (unsigned int)(qstart + t * 16 + n16);
                    }
                }
            }
        }
        bc0 = bn0; bc1 = bn1; bc2 = bn2; bc3 = bn3;
        lp = nlp;
    }

    if (MODE == 0) {
        #pragma unroll
        for (int rf = 0; rf < 8; ++rf)
            #pragma unroll
            for (int r = 0; r < 4; ++r) {
                float v = rmax[rf][r];
                v = fmaxf(v, __shfl_xor(v, 1));
                v = fmaxf(v, __shfl_xor(v, 2));
                v = fmaxf(v, __shfl_xor(v, 4));
                v = fmaxf(v, __shfl_xor(v, 8));
                if (n16 == 0)
                    atomicMax(&mbest[rowbase + rf * 16 + quad * 4 + r], ordered_bits(v));
            }
    }
}

// ---------- K5: exact fp32 re-rank of candidates ----------
__global__ void k_rerank(const float* __restrict__ pn, const float* __restrict__ queue,
                         const unsigned int* __restrict__ cnt,
                         const unsigned long long* __restrict__ cand,
                         unsigned long long* __restrict__ best) {
    int widx = (blockIdx.x * 256 + threadIdx.x) >> 6;
    int lane = threadIdx.x & 63;
    unsigned int n = *cnt; if (n > CAND_CAP) n = CAND_CAP;
    if ((unsigned int)widx >= n) return;
    unsigned long long c = cand[widx];
    unsigned int row = (unsigned int)(c >> 32);
    unsigned int q = (unsigned int)c;
    float2 a = ((const float2*)(pn + (size_t)row * 128))[lane];
    float2 b = ((const float2*)(queue + (size_t)q * 128))[lane];
    float d = a.x * b.x + a.y * b.y;
    #pragma unroll
    for (int o = 32; o; o >>= 1) d += __shfl_xor(d, o);
    if (lane == 0) {
        unsigned long long pk = ((unsigned long long)ordered_bits(d) << 32)
                              | (unsigned long long)(unsigned int)(~q);
        atomicMax(&best[row], pk);
    }
}

// ---------- K6: gather nn rows from queue -> bf16 ----------
__global__ void k_gather(const float* __restrict__ queue,
                         const unsigned long long* __restrict__ best,
                         short* __restrict__ nnb) {
    int row = blockIdx.x;               // 0..4095
    int t = threadIdx.x;                // 0..63
    unsigned int idx = ~(unsigned int)(best[row] & 0xFFFFFFFFull);
    idx &= 0xFFFFu;                     // safety clamp (only hit on cand overflow)
    float2 v = ((const float2*)(queue + (size_t)idx * 128))[t];
    unsigned int pk = (unsigned int)(unsigned short)bf_rne(v.x)
                    | ((unsigned int)(unsigned short)bf_rne(v.y) << 16);
    ((unsigned int*)(nnb + (size_t)row * 128))[t] = pk;
}

// ---------- K7: M = nnb(bf16) @ pn(fp32)^T, fp32 accumulate ----------
__global__ __launch_bounds__(256) void k_gemm_bt(const short* __restrict__ Ab,
                                                 const float* __restrict__ B,
                                                 float* __restrict__ C) {
    __shared__ __align__(16) float al[64 * S];
    __shared__ __align__(16) float bl[64 * S];
    int tid = threadIdx.x;
    const short8* asrc = (const short8*)(Ab + (size_t)blockIdx.x * 64 * 128);
    #pragma unroll
    for (int i = tid; i < 1024; i += 256) {       // 64x128 bf16 -> fp32 LDS
        short8 v = asrc[i];
        int r = i >> 4, c = (i & 15) * 8;
        float* dst = &al[r * S + c];
        #pragma unroll
        for (int j = 0; j < 8; ++j) dst[j] = bf2f(v[j]);
    }
    const float4* bsrc = (const float4*)(B + (size_t)blockIdx.y * 64 * 128);
    #pragma unroll
    for (int i = tid; i < 2048; i += 256) {
        int r = i >> 5, c = i & 31;
        *(float4*)&bl[r * S + c * 4] = bsrc[i];
    }
    __syncthreads();
    int ty = tid >> 4, tx = tid & 15;
    float acc[4][4] = {};
    #pragma unroll 2
    for (int k = 0; k < 128; k += 4) {
        float4 a[4], b[4];
        #pragma unroll
        for (int i = 0; i < 4; ++i) a[i] = *(const float4*)&al[(ty + 16 * i) * S + k];
        #pragma unroll
        for (int j = 0; j < 4; ++j) b[j] = *(const float4*)&bl[(tx + 16 * j) * S + k];
        #pragma unroll
        for (int i = 0; i < 4; ++i)
            #pragma unroll
            for (int j = 0; j < 4; ++j)
                acc[i][j] += a[i].x * b[j].x + a[i].y * b[j].y +
                             a[i].z * b[j].z + a[i].w * b[j].w;
    }
    int rowbase = blockIdx.x * 64, colbase = blockIdx.y * 64;
    #pragma unroll
    for (int i = 0; i < 4; ++i)
        #pragma unroll
        for (int j = 0; j < 4; ++j)
            C[(size_t)(rowbase + ty + 16 * i) * 2048 + (colbase + tx + 16 * j)] = acc[i][j];
}

// ---------- K8: row-wise LSE minus diag ----------
__global__ void k_row_lse(const float* __restrict__ M, float* __restrict__ out) {
    int row = blockIdx.x;
    int tid = threadIdx.x;
    __shared__ float sm[256], ssb[256];
    float m = -1e30f, s = 0.0f;
    for (int j = tid; j < 2048; j += 256) {
        float x = M[(size_t)row * 2048 + j] * SCALE;
        if (x > m) { s = s * expf(m - x) + 1.0f; m = x; }
        else s += expf(x - m);
    }
    sm[tid] = m; ssb[tid] = s; __syncthreads();
    for (int w = 128; w; w >>= 1) {
        if (tid < w) {
            float m2 = sm[tid + w], s2 = ssb[tid + w];
            float mm = fmaxf(sm[tid], m2);
            ssb[tid] = ssb[tid] * expf(sm[tid] - mm) + s2 * expf(m2 - mm);
            sm[tid] = mm;
        }
        __syncthreads();
    }
    if (tid == 0)
        out[row] = sm[0] + logf(ssb[0]) - M[(size_t)row * 2048 + row] * SCALE;
}

// ---------- K9: column-wise LSE minus diag ----------
__global__ void k_col_lse(const float* __restrict__ M, float* __restrict__ out) {
    int c0 = blockIdx.x * 64;
    int tid = threadIdx.x;
    int col = c0 + (tid & 63);
    int g = tid >> 6;
    __shared__ float sm[256], ssb[256];
    float m = -1e30f, s = 0.0f;
    for (int r = g; r < 2048; r += 4) {
        float x = M[(size_t)r * 2048 + col] * SCALE;
        if (x > m) { s = s * expf(m - x) + 1.0f; m = x; }
        else s += expf(x - m);
    }
    sm[tid] = m; ssb[tid] = s; __syncthreads();
    if (tid < 64) {
        float mm = sm[tid], ss = ssb[tid];
        #pragma unroll
        for (int gg = 1; gg < 4; ++gg) {
            float m2 = sm[tid + 64 * gg], s2 = ssb[tid + 64 * gg];
            float mx = fmaxf(mm, m2);
            ss = ss * expf(mm - mx) + s2 * expf(m2 - mx);
            mm = mx;
        }
        out[col] = mm + logf(ss) - M[(size_t)col * 2048 + col] * SCALE;
    }
}

extern "C" void kernel_launch(void* const* d_in, const int* in_sizes, int n_in,
                              void* d_out, int out_size, void* d_ws, size_t ws_size,
                              hipStream_t stream) {
    const float* p1    = (const float*)d_in[0];   // [2048,128]
    const float* p2    = (const float*)d_in[1];   // [2048,128]
    const float* queue = (const float*)d_in[2];   // [65536,128]
    float* out = (float*)d_out;                   // [8192]

    char* w = (char*)d_ws;                        // total footprint ~19.2 MiB
    float* pn  = (float*)w;                               // 2 MB fp32 [4096,128]
    short* nnb = (short*)(w + (2u << 20));                // 1 MB bf16 [4096,128]
    short* qb  = (short*)(w + (3u << 20));                // 16 MB bf16 [65536,128]
    float* M   = (float*)(w + (3u << 20));                // 16 MB fp32, aliases qb (dead)
    unsigned int* mbest = (unsigned int*)(w + (19u << 20));               // 16 KB
    unsigned long long* best = (unsigned long long*)(w + (19u << 20) + (16u << 10)); // 32 KB
    unsigned int* cnt = (unsigned int*)(w + (19u << 20) + (48u << 10));   // 64 B
    unsigned long long* cand = (unsigned long long*)(w + (19u << 20) + (48u << 10) + 64); // 128 KB

    k_prep<<<4096, 64, 0, stream>>>(p1, p2, pn, mbest, best, cnt);
    k_qcvt<<<4096, 256, 0, stream>>>(queue, qb);
    k_screen<0><<<dim3(32, 16), 256, 0, stream>>>(pn, qb, mbest, cnt, cand);
    k_screen<1><<<dim3(32, 16), 256, 0, stream>>>(pn, qb, mbest, cnt, cand);
    k_rerank<<<4096, 256, 0, stream>>>(pn, queue, cnt, cand, best);
    k_gather<<<4096, 64, 0, stream>>>(queue, best, nnb);

    // M1 = nn1 @ p2n^T -> rows: loss[0..2047], cols: loss[2048..4095]
    k_gemm_bt<<<dim3(32, 32), 256, 0, stream>>>(nnb, pn + 2048 * 128, M);
    k_row_lse<<<2048, 256, 0, stream>>>(M, out);
    k_col_lse<<<32, 256, 0, stream>>>(M, out + 2048);

    // M2 = nn2 @ p1n^T -> rows: loss[4096..6143], cols: loss[6144..8191]
    k_gemm_bt<<<dim3(32, 32), 256, 0, stream>>>(nnb + 2048 * 128, pn, M);
    k_row_lse<<<2048, 256, 0, stream>>>(M, out + 4096);
    k_col_lse<<<32, 256, 0, stream>>>(M, out + 6144);
}

// Round 3
// 337.594 us; speedup vs baseline: 5.0119x; 2.1617x over previous
//
#include <hip/hip_runtime.h>

#define S 132                 // padded LDS row stride (floats) for gemm tiles
#define SCALE 10.0f           // 1 / TEMPERATURE
#define EPS_MARGIN 0.008f     // 2 * (bf16 unit-vector dot hard error bound 2^-8)
#define CAND_CAP 16384

typedef __attribute__((ext_vector_type(8))) short short8;
typedef __attribute__((ext_vector_type(4))) float floatx4;

#define MFMA16(a, b, c) __builtin_amdgcn_mfma_f32_16x16x32_bf16((a), (b), (c), 0, 0, 0)

// ---------- helpers ----------
__device__ __forceinline__ unsigned int ordered_bits(float f) {
    unsigned int b = __float_as_uint(f);
    return (b & 0x80000000u) ? ~b : (b | 0x80000000u);
}
__device__ __forceinline__ float from_ordered(unsigned int u) {
    return __uint_as_float((u & 0x80000000u) ? (u ^ 0x80000000u) : ~u);
}
__device__ __forceinline__ short bf_rne(float x) {   // fp32 -> bf16 bits, RNE
    unsigned int u = __float_as_uint(x);
    return (short)((u + 0x7FFFu + ((u >> 16) & 1u)) >> 16);
}
__device__ __forceinline__ float bf2f(short s) {
    return __uint_as_float(((unsigned int)(unsigned short)s) << 16);
}

// ---------- K1: l2-normalize p1,p2 -> pn fp32; init mbest/best/cnt/sums -----
__global__ void k_prep(const float* __restrict__ p1, const float* __restrict__ p2,
                       float* __restrict__ pn, unsigned int* __restrict__ mbest,
                       unsigned long long* __restrict__ best, unsigned int* __restrict__ cnt,
                       float* __restrict__ sums /* rs1,cs1,rs2,cs2 : 8192 floats */) {
    int row = blockIdx.x;               // 0..4095
    int t = threadIdx.x;                // 0..63
    const float* src = (row < 2048) ? (p1 + (size_t)row * 128)
                                    : (p2 + (size_t)(row - 2048) * 128);
    float2 v = ((const float2*)src)[t];
    float ss = v.x * v.x + v.y * v.y;
    #pragma unroll
    for (int o = 32; o; o >>= 1) ss += __shfl_xor(ss, o);
    float inv = 1.0f / sqrtf(ss);
    float2 o2; o2.x = v.x * inv; o2.y = v.y * inv;
    ((float2*)(pn + (size_t)row * 128))[t] = o2;
    if (t == 0) { mbest[row] = 0u; best[row] = 0ULL; if (row == 0) *cnt = 0u; }
    if (row < 128) sums[row * 64 + t] = 0.0f;
}

// ---------- K2: queue fp32 -> qb bf16 ----------
__global__ void k_qcvt(const float* __restrict__ queue, short* __restrict__ qb) {
    size_t i = ((size_t)blockIdx.x * 256 + threadIdx.x) * 8;
    float4 f0 = *(const float4*)(queue + i);
    float4 f1 = *(const float4*)(queue + i + 4);
    short8 o;
    o[0] = bf_rne(f0.x); o[1] = bf_rne(f0.y); o[2] = bf_rne(f0.z); o[3] = bf_rne(f0.w);
    o[4] = bf_rne(f1.x); o[5] = bf_rne(f1.y); o[6] = bf_rne(f1.z); o[7] = bf_rne(f1.w);
    *(short8*)(qb + i) = o;
}

// ---------- K3/K4: bf16 MFMA screen. MODE 0: per-row max; MODE 1: candidates --
template <int MODE>
__global__ __launch_bounds__(256, 2) void k_screen(const float* __restrict__ pn,
                                                   const short* __restrict__ qb,
                                                   unsigned int* __restrict__ mbest,
                                                   unsigned int* __restrict__ cnt,
                                                   unsigned long long* __restrict__ cand) {
    int tid = threadIdx.x;
    int lane = tid & 63, wv = tid >> 6;
    int n16 = lane & 15, quad = lane >> 4;
    int rowbase = blockIdx.x * 128;
    int qstart = blockIdx.y * 4096 + wv * 1024;

    short8 A[8][4];
    #pragma unroll
    for (int rf = 0; rf < 8; ++rf) {
        const float* ap = pn + (size_t)(rowbase + rf * 16 + n16) * 128 + quad * 8;
        #pragma unroll
        for (int k = 0; k < 4; ++k) {
            float4 f0 = *(const float4*)(ap + 32 * k);
            float4 f1 = *(const float4*)(ap + 32 * k + 4);
            short8 a;
            a[0] = bf_rne(f0.x); a[1] = bf_rne(f0.y); a[2] = bf_rne(f0.z); a[3] = bf_rne(f0.w);
            a[4] = bf_rne(f1.x); a[5] = bf_rne(f1.y); a[6] = bf_rne(f1.z); a[7] = bf_rne(f1.w);
            A[rf][k] = a;
        }
    }

    float rmax[8][4];
    float thr[8][4];
    #pragma unroll
    for (int rf = 0; rf < 8; ++rf)
        #pragma unroll
        for (int r = 0; r < 4; ++r) {
            if (MODE == 0) rmax[rf][r] = -1e30f;
            else thr[rf][r] = from_ordered(mbest[rowbase + rf * 16 + quad * 4 + r]) - EPS_MARGIN;
        }

    const short* lp = qb + (size_t)(qstart + n16) * 128 + quad * 8;
    short8 bc0 = *(const short8*)(lp), bc1 = *(const short8*)(lp + 32),
           bc2 = *(const short8*)(lp + 64), bc3 = *(const short8*)(lp + 96);
    floatx4 zero = {0.0f, 0.0f, 0.0f, 0.0f};

    for (int t = 0; t < 64; ++t) {
        const short* nlp = lp + 2048;
        short8 bn0 = *(const short8*)(nlp), bn1 = *(const short8*)(nlp + 32),
               bn2 = *(const short8*)(nlp + 64), bn3 = *(const short8*)(nlp + 96);
        #pragma unroll
        for (int rf = 0; rf < 8; ++rf) {
            floatx4 acc = MFMA16(A[rf][0], bc0, zero);
            acc = MFMA16(A[rf][1], bc1, acc);
            acc = MFMA16(A[rf][2], bc2, acc);
            acc = MFMA16(A[rf][3], bc3, acc);
            if (MODE == 0) {
                #pragma unroll
                for (int r = 0; r < 4; ++r) rmax[rf][r] = fmaxf(rmax[rf][r], acc[r]);
            } else {
                #pragma unroll
                for (int r = 0; r < 4; ++r) {
                    if (acc[r] > thr[rf][r]) {
                        unsigned int pos = atomicAdd(cnt, 1u);
                        if (pos < CAND_CAP)
                            cand[pos] = ((unsigned long long)(unsigned int)(rowbase + rf * 16 + quad * 4 + r) << 32)
                                      | (unsigned int)(qstart + t * 16 + n16);
                    }
                }
            }
        }
        bc0 = bn0; bc1 = bn1; bc2 = bn2; bc3 = bn3;
        lp = nlp;
    }

    if (MODE == 0) {
        #pragma unroll
        for (int rf = 0; rf < 8; ++rf)
            #pragma unroll
            for (int r = 0; r < 4; ++r) {
                float v = rmax[rf][r];
                v = fmaxf(v, __shfl_xor(v, 1));
                v = fmaxf(v, __shfl_xor(v, 2));
                v = fmaxf(v, __shfl_xor(v, 4));
                v = fmaxf(v, __shfl_xor(v, 8));
                if (n16 == 0)
                    atomicMax(&mbest[rowbase + rf * 16 + quad * 4 + r], ordered_bits(v));
            }
    }
}

// ---------- K5: exact fp32 re-rank of candidates ----------
__global__ void k_rerank(const float* __restrict__ pn, const float* __restrict__ queue,
                         const unsigned int* __restrict__ cnt,
                         const unsigned long long* __restrict__ cand,
                         unsigned long long* __restrict__ best) {
    int widx = (blockIdx.x * 256 + threadIdx.x) >> 6;
    int lane = threadIdx.x & 63;
    unsigned int n = *cnt; if (n > CAND_CAP) n = CAND_CAP;
    if ((unsigned int)widx >= n) return;
    unsigned long long c = cand[widx];
    unsigned int row = (unsigned int)(c >> 32);
    unsigned int q = (unsigned int)c;
    float2 a = ((const float2*)(pn + (size_t)row * 128))[lane];
    float2 b = ((const float2*)(queue + (size_t)q * 128))[lane];
    float d = a.x * b.x + a.y * b.y;
    #pragma unroll
    for (int o = 32; o; o >>= 1) d += __shfl_xor(d, o);
    if (lane == 0) {
        unsigned long long pk = ((unsigned long long)ordered_bits(d) << 32)
                              | (unsigned long long)(unsigned int)(~q);
        atomicMax(&best[row], pk);
    }
}

// ---------- K6: gather nn rows from queue -> bf16 ----------
__global__ void k_gather(const float* __restrict__ queue,
                         const unsigned long long* __restrict__ best,
                         short* __restrict__ nnb) {
    int row = blockIdx.x;
    int t = threadIdx.x;
    unsigned int idx = ~(unsigned int)(best[row] & 0xFFFFFFFFull);
    idx &= 0xFFFFu;
    float2 v = ((const float2*)(queue + (size_t)idx * 128))[t];
    unsigned int pk = (unsigned int)(unsigned short)bf_rne(v.x)
                    | ((unsigned int)(unsigned short)bf_rne(v.y) << 16);
    ((unsigned int*)(nnb + (size_t)row * 128))[t] = pk;
}

// ---------- K7: fused  A(bf16) @ B(fp32)^T  ->  exp-partial row/col sums ------
// Fixed-shift LSE: logits = 10*sim, sim in [-1,1]  =>  LSE = 10 + log(sum exp(x-10)).
// Each 64x64 tile: e = exp(10*sim - 10); LDS-reduce to 64 row / 64 col partials;
// atomicAdd to rowsum/colsum. Diagonal blocks also store diag sim.
__global__ __launch_bounds__(256) void k_gemm_lse(const short* __restrict__ Ab,
                                                  const float* __restrict__ B,
                                                  float* __restrict__ rowsum,
                                                  float* __restrict__ colsum,
                                                  float* __restrict__ diag) {
    __shared__ __align__(16) float al[64 * S];
    __shared__ __align__(16) float bl[64 * S];
    __shared__ float red[64][17];
    int tid = threadIdx.x;
    const short8* asrc = (const short8*)(Ab + (size_t)blockIdx.x * 64 * 128);
    #pragma unroll
    for (int i = tid; i < 1024; i += 256) {
        short8 v = asrc[i];
        int r = i >> 4, c = (i & 15) * 8;
        float* dst = &al[r * S + c];
        #pragma unroll
        for (int j = 0; j < 8; ++j) dst[j] = bf2f(v[j]);
    }
    const float4* bsrc = (const float4*)(B + (size_t)blockIdx.y * 64 * 128);
    #pragma unroll
    for (int i = tid; i < 2048; i += 256) {
        int r = i >> 5, c = i & 31;
        *(float4*)&bl[r * S + c * 4] = bsrc[i];
    }
    __syncthreads();
    int ty = tid >> 4, tx = tid & 15;
    float acc[4][4] = {};
    #pragma unroll 2
    for (int k = 0; k < 128; k += 4) {
        float4 a[4], b[4];
        #pragma unroll
        for (int i = 0; i < 4; ++i) a[i] = *(const float4*)&al[(ty + 16 * i) * S + k];
        #pragma unroll
        for (int j = 0; j < 4; ++j) b[j] = *(const float4*)&bl[(tx + 16 * j) * S + k];
        #pragma unroll
        for (int i = 0; i < 4; ++i)
            #pragma unroll
            for (int j = 0; j < 4; ++j)
                acc[i][j] += a[i].x * b[j].x + a[i].y * b[j].y +
                             a[i].z * b[j].z + a[i].w * b[j].w;
    }
    int rowbase = blockIdx.x * 64, colbase = blockIdx.y * 64;

    // exponentials + per-thread partials
    float e[4][4], rs[4], cs[4];
    #pragma unroll
    for (int i = 0; i < 4; ++i) { rs[i] = 0.0f; cs[i] = 0.0f; }
    #pragma unroll
    for (int i = 0; i < 4; ++i)
        #pragma unroll
        for (int j = 0; j < 4; ++j) {
            e[i][j] = __expf(acc[i][j] * SCALE - 10.0f);
            rs[i] += e[i][j];
        }
    #pragma unroll
    for (int j = 0; j < 4; ++j)
        #pragma unroll
        for (int i = 0; i < 4; ++i) cs[j] += e[i][j];

    // diagonal capture (exact sim, not exp)
    if (rowbase == colbase && ty == tx) {
        #pragma unroll
        for (int i = 0; i < 4; ++i) diag[rowbase + ty + 16 * i] = acc[i][i];
    }

    // rows: red[ty+16i][tx] = rs[i]; 64 threads each sum 16
    #pragma unroll
    for (int i = 0; i < 4; ++i) red[ty + 16 * i][tx] = rs[i];
    __syncthreads();
    if (tid < 64) {
        float s = 0.0f;
        #pragma unroll
        for (int x = 0; x < 16; ++x) s += red[tid][x];
        atomicAdd(&rowsum[rowbase + tid], s);
    }
    __syncthreads();
    #pragma unroll
    for (int j = 0; j < 4; ++j) red[tx + 16 * j][ty] = cs[j];
    __syncthreads();
    if (tid < 64) {
        float s = 0.0f;
        #pragma unroll
        for (int x = 0; x < 16; ++x) s += red[tid][x];
        atomicAdd(&colsum[colbase + tid], s);
    }
}

// ---------- K8: final loss from sums + diag ----------
__global__ void k_final(const float* __restrict__ sums /* rs1,cs1,rs2,cs2 */,
                        const float* __restrict__ dg1, const float* __restrict__ dg2,
                        float* __restrict__ out) {
    int idx = blockIdx.x * 256 + threadIdx.x;    // 0..8191
    int seg = idx >> 11, r = idx & 2047;
    float s = sums[seg * 2048 + r];
    float d = (seg < 2) ? dg1[r] : dg2[r];
    out[idx] = 10.0f + logf(s) - d * SCALE;
}

extern "C" void kernel_launch(void* const* d_in, const int* in_sizes, int n_in,
                              void* d_out, int out_size, void* d_ws, size_t ws_size,
                              hipStream_t stream) {
    const float* p1    = (const float*)d_in[0];   // [2048,128]
    const float* p2    = (const float*)d_in[1];   // [2048,128]
    const float* queue = (const float*)d_in[2];   // [65536,128]
    float* out = (float*)d_out;                   // [8192]

    char* w = (char*)d_ws;
    float* pn  = (float*)w;                               // 2 MB fp32 [4096,128]
    short* nnb = (short*)(w + (2u << 20));                // 1 MB bf16 [4096,128]
    short* qb  = (short*)(w + (3u << 20));                // 16 MB bf16 [65536,128]
    unsigned int* mbest = (unsigned int*)(w + (19u << 20));               // 16 KB
    unsigned long long* best = (unsigned long long*)(w + (19u << 20) + (16u << 10)); // 32 KB
    unsigned int* cnt = (unsigned int*)(w + (19u << 20) + (48u << 10));   // 64 B
    unsigned long long* cand = (unsigned long long*)(w + (19u << 20) + (48u << 10) + 64); // 128 KB
    float* sums = (float*)(w + (19u << 20) + (192u << 10));  // rs1,cs1,rs2,cs2: 32 KB
    float* dg1  = sums + 8192;                               // 8 KB
    float* dg2  = dg1 + 2048;                                // 8 KB

    k_prep<<<4096, 64, 0, stream>>>(p1, p2, pn, mbest, best, cnt, sums);
    k_qcvt<<<4096, 256, 0, stream>>>(queue, qb);
    k_screen<0><<<dim3(32, 16), 256, 0, stream>>>(pn, qb, mbest, cnt, cand);
    k_screen<1><<<dim3(32, 16), 256, 0, stream>>>(pn, qb, mbest, cnt, cand);
    k_rerank<<<4096, 256, 0, stream>>>(pn, queue, cnt, cand, best);
    k_gather<<<4096, 64, 0, stream>>>(queue, best, nnb);

    // M1 = nn1 @ p2n^T : rows -> loss[0..2047], cols -> loss[2048..4095]
    k_gemm_lse<<<dim3(32, 32), 256, 0, stream>>>(nnb, pn + 2048 * 128,
                                                 sums, sums + 2048, dg1);
    // M2 = nn2 @ p1n^T : rows -> loss[4096..6143], cols -> loss[6144..8191]
    k_gemm_lse<<<dim3(32, 32), 256, 0, stream>>>(nnb + 2048 * 128, pn,
                                                 sums + 4096, sums + 6144, dg2);
    k_final<<<32, 256, 0, stream>>>(sums, dg1, dg2, out);
}